// Round 5
// baseline (1182.453 us; speedup 1.0000x reference)
//
#include <hip/hip_runtime.h>
#include <stdint.h>

#define B_DIM 8
#define S_DIM 4096
#define F_DIM 512
#define H_DIM 2048
#define W_DIM 16
#define L_DIM 4081               // S - W + 1
#define M_TOT 32648              // B * L
#define K1_DIM 8192              // W * F
#define SXF 2097152              // S * F

typedef __bf16 bf16x8 __attribute__((ext_vector_type(8)));
typedef float f32x4 __attribute__((ext_vector_type(4)));

__device__ __forceinline__ unsigned short f2bf(float f) {
  union { float f; uint32_t u; } a; a.f = f;
  return (unsigned short)((a.u + 0x7fffu + ((a.u >> 16) & 1u)) >> 16);
}

__device__ __forceinline__ void async16(const void* g, void* l) {
  __builtin_amdgcn_global_load_lds(
      (__attribute__((address_space(1))) void*)(uintptr_t)g,
      (__attribute__((address_space(3))) void*)l, 16, 0, 0);
}

#define SBAR   __builtin_amdgcn_s_barrier()
#define SCHED0 __builtin_amdgcn_sched_barrier(0)
#define PRIO1  __builtin_amdgcn_s_setprio(1)
#define PRIO0  __builtin_amdgcn_s_setprio(0)
#define VM0    asm volatile("s_waitcnt vmcnt(0)" ::: "memory")
#define VM2    asm volatile("s_waitcnt vmcnt(2)" ::: "memory")
#define VM4    asm volatile("s_waitcnt vmcnt(4)" ::: "memory")

// 4 MFMAs: acc[T][U], acc[T][U+1] over ks0 (AK0,b0/b2) and ks1 (AK1,b1/b3)
#define MACC(T, U, AK0, AK1) \
  acc[T][(U)+0] = __builtin_amdgcn_mfma_f32_16x16x32_bf16(AK0, b0, acc[T][(U)+0], 0, 0, 0); \
  acc[T][(U)+0] = __builtin_amdgcn_mfma_f32_16x16x32_bf16(AK1, b1, acc[T][(U)+0], 0, 0, 0); \
  acc[T][(U)+1] = __builtin_amdgcn_mfma_f32_16x16x32_bf16(AK0, b2, acc[T][(U)+1], 0, 0, 0); \
  acc[T][(U)+1] = __builtin_amdgcn_mfma_f32_16x16x32_bf16(AK1, b3, acc[T][(U)+1], 0, 0, 0);

// one quadrant x K=64: 16 MFMAs
#define MFMA16(TB, UB) \
  MACC((TB)+0, UB, a0, a1) MACC((TB)+1, UB, a2, a3) \
  MACC((TB)+2, UB, a4, a5) MACC((TB)+3, UB, a6, a7)

// A-half (4 row-tiles x 2 ks) : 8 x ds_read_b128
#define RD_A(TB) \
  a0 = *(const bf16x8*)(p + aoff  + (TB)*2048);        a1 = *(const bf16x8*)(p + aoff1 + (TB)*2048); \
  a2 = *(const bf16x8*)(p + aoff  + (TB)*2048 + 2048); a3 = *(const bf16x8*)(p + aoff1 + (TB)*2048 + 2048); \
  a4 = *(const bf16x8*)(p + aoff  + (TB)*2048 + 4096); a5 = *(const bf16x8*)(p + aoff1 + (TB)*2048 + 4096); \
  a6 = *(const bf16x8*)(p + aoff  + (TB)*2048 + 6144); a7 = *(const bf16x8*)(p + aoff1 + (TB)*2048 + 6144);

// B-half (2 col-tiles x 2 ks) : 4 x ds_read_b128
#define RD_B(UB) \
  b0 = *(const bf16x8*)(p + boff  + (UB)*2048);        b1 = *(const bf16x8*)(p + boff1 + (UB)*2048); \
  b2 = *(const bf16x8*)(p + boff  + (UB)*2048 + 2048); b3 = *(const bf16x8*)(p + boff1 + (UB)*2048 + 2048);

// ---------------- GEMM1: h = relu(x_hankel @ w1 + b1) ----------------------
// 256x256 tile, BK=64, 8 waves (2M x 4N, each 128x64). r3 staging/layout
// (row-major swizzled LDS, 128 B granule) + m201-style FINE PHASE
// INTERLEAVE: 4 phases/K-tile in serpentine quadrant order
//   q0:(mh0,nh0) q1:(mh0,nh1) q2:(mh1,nh1) q3:(mh1,nh0)
// so A-halves are read once (q0,q2) and only B re-reads (28 b128/wave/tile,
// max 12 live frag regs - no VGPR growth). Each phase: {reads; 2 stage
// issues; barrier; lgkmcnt(0)+sched_barrier(0); setprio(1); 16 MFMA;
// setprio(0); [counted vmcnt]; barrier}. Small read groups break r3/r4's
// [12-read burst -> wait -> 32 MFMA] serialization (the measured ~2100
// cy/tile of exposed LDS time at 50% MfmaUtil).
// Counted vmcnt (never 0 in steady state): stages for tile T+1 issue as
// B01(q0) B23(q1) A02(q2) A13(q3). Mid-tile wait = vmcnt(4): oldest
// outstanding = A13(T) (issued T-1.q3), forced landed before q2 reads it;
// tile-end wait = vmcnt(2): forces B01,B23,A02(T+1) landed (q0 consumes),
// A13(T+1) may remain in flight. Last tile drains VM0.
__global__ __launch_bounds__(512, 2) void gemm1_kernel(
    const unsigned short* __restrict__ xb,
    const unsigned short* __restrict__ w1t,
    const float* __restrict__ bias1,
    unsigned short* __restrict__ h)
{
  __shared__ alignas(16) unsigned char lsm[131072];  // [2][A 32K | B 32K]

  const int tid  = threadIdx.x;
  const int lane = tid & 63;
  const int wave = tid >> 6;           // 0..7
  const int id = blockIdx.x;
  const int nt = id & 7;               // XCD-pinned B column
  const int mt = id >> 3;

  // ---- staging decode: thread t covers row rr, 16B slot (t&7),
  //      swizzled global col-group ((t&7) ^ (rr&7)) ----
  const int rr   = tid >> 3;           // 0..63
  const int xoro = (((tid & 7) ^ (rr & 7)) << 3);  // element offset in row

  const unsigned short* pA0; const unsigned short* pA1;
  const unsigned short* pA2; const unsigned short* pA3;
#define MKPA(PS, S) { \
    int m = mt * 256 + (S) * 64 + rr; \
    if (m >= M_TOT) m = M_TOT - 1; \
    const int b_ = m / L_DIM, l_ = m - b_ * L_DIM; \
    PS = xb + (size_t)b_ * SXF + (size_t)l_ * F_DIM + xoro; }
  MKPA(pA0, 0) MKPA(pA1, 1) MKPA(pA2, 2) MKPA(pA3, 3)
#undef MKPA
  const unsigned short* pB0 = w1t + (size_t)(nt * 256 +   0 + rr) * K1_DIM + xoro;
  const unsigned short* pB1 = w1t + (size_t)(nt * 256 +  64 + rr) * K1_DIM + xoro;
  const unsigned short* pB2 = w1t + (size_t)(nt * 256 + 128 + rr) * K1_DIM + xoro;
  const unsigned short* pB3 = w1t + (size_t)(nt * 256 + 192 + rr) * K1_DIM + xoro;

  const int wm = wave >> 2;            // 0..1 : 128-row band
  const int wn = wave & 3;             // 0..3 : 64-col band

  // ---- consumer lane bases (swizzled): row = band + (lane&15),
  //      slot = (ks*4 + lane>>4) ^ (lane&7); ks1 = ks0 ^ 64 bytes ----
  const int l15 = lane & 15;
  const int slot0 = ((lane >> 4) ^ (lane & 7)) << 4;
  const int aoff  = (wm * 128 + l15) * 128 + slot0;            // A at +0
  const int aoff1 = aoff ^ 64;
  const int boff  = 32768 + (wn * 64 + l15) * 128 + slot0;     // B at +32K
  const int boff1 = boff ^ 64;

  f32x4 acc[8][4] = {};

  const int KT = K1_DIM / 64;          // 128 K-tiles

#define STAGE_B01(TT) { const size_t ko_ = (size_t)(TT) * 64; \
    unsigned char* d_ = lsm + (((TT) & 1) << 16) + 32768 + tid * 16; \
    async16(pB0 + ko_, d_); async16(pB1 + ko_, d_ + 8192); }
#define STAGE_B23(TT) { const size_t ko_ = (size_t)(TT) * 64; \
    unsigned char* d_ = lsm + (((TT) & 1) << 16) + 32768 + tid * 16; \
    async16(pB2 + ko_, d_ + 16384); async16(pB3 + ko_, d_ + 24576); }
#define STAGE_A02(TT) { const size_t ko_ = (size_t)(TT) * 64; \
    unsigned char* d_ = lsm + (((TT) & 1) << 16) + tid * 16; \
    async16(pA0 + ko_, d_); async16(pA2 + ko_, d_ + 16384); }
#define STAGE_A13(TT) { const size_t ko_ = (size_t)(TT) * 64; \
    unsigned char* d_ = lsm + (((TT) & 1) << 16) + tid * 16; \
    async16(pA1 + ko_, d_ + 8192); async16(pA3 + ko_, d_ + 24576); }

  // prologue: stage tile 0 fully, drain once, go
  STAGE_B01(0); STAGE_B23(0); STAGE_A02(0); STAGE_A13(0);
  VM0; SBAR; SCHED0;

  for (int kt = 0; kt < KT; ++kt) {
    const unsigned char* p = lsm + ((kt & 1) << 16);
    const bool last = (kt >= KT - 1);
    bf16x8 a0, a1, a2, a3, a4, a5, a6, a7, b0, b1, b2, b3;

    // q0: quadrant (mh0, nh0)
    RD_A(0); RD_B(0);
    if (!last) STAGE_B01(kt + 1);
    SBAR; asm volatile("s_waitcnt lgkmcnt(0)" ::: "memory"); SCHED0;
    PRIO1; MFMA16(0, 0); PRIO0;
    SBAR;

    // q1: quadrant (mh0, nh1) - A kept live, new B
    RD_B(2);
    if (!last) STAGE_B23(kt + 1);
    SBAR; asm volatile("s_waitcnt lgkmcnt(0)" ::: "memory"); SCHED0;
    PRIO1; MFMA16(0, 2); PRIO0;
    if (last) { VM0; } else { VM4; }   // A13(kt) landed before q2 reads it
    SBAR;

    // q2: quadrant (mh1, nh1) - B kept live, new A
    RD_A(4);
    if (!last) STAGE_A02(kt + 1);
    SBAR; asm volatile("s_waitcnt lgkmcnt(0)" ::: "memory"); SCHED0;
    PRIO1; MFMA16(4, 2); PRIO0;
    SBAR;

    // q3: quadrant (mh1, nh0) - A kept live, re-read B(nh0)
    RD_B(0);
    if (!last) STAGE_A13(kt + 1);
    SBAR; asm volatile("s_waitcnt lgkmcnt(0)" ::: "memory"); SCHED0;
    PRIO1; MFMA16(4, 0); PRIO0;
    if (last) { VM0; } else { VM2; }   // B01,B23,A02(kt+1) landed for next q0
    SBAR;
  }
#undef STAGE_B01
#undef STAGE_B23
#undef STAGE_A02
#undef STAGE_A13

  // C/D layout: col = lane&15, row = (lane>>4)*4 + reg
  const int ncol = nt * 256 + wn * 64 + l15;
  const int mrow = mt * 256 + wm * 128 + (lane >> 4) * 4;
#pragma unroll
  for (int u = 0; u < 4; ++u) {
    const int n = ncol + u * 16;
    const float bv = bias1[n];
#pragma unroll
    for (int t = 0; t < 8; ++t) {
#pragma unroll
      for (int r = 0; r < 4; ++r) {
        const int m = mrow + t * 16 + r;
        if (m < M_TOT) {
          float v = acc[t][u][r] + bv;
          v = v > 0.f ? v : 0.f;
          h[(size_t)m * H_DIM + n] = f2bf(v);
        }
      }
    }
  }
}

// ---------------- GEMM2: y = h @ w2 + b2, same structure, KT=32 ------------
__global__ __launch_bounds__(512, 2) void gemm2_kernel(
    const unsigned short* __restrict__ hmat,
    const unsigned short* __restrict__ w2t,   // [512][2048]
    const float* __restrict__ bias2,
    float* __restrict__ out)
{
  __shared__ alignas(16) unsigned char lsm[131072];

  const int tid  = threadIdx.x;
  const int lane = tid & 63;
  const int wave = tid >> 6;
  const int id = blockIdx.x;
  const int nt = id & 1;               // 2 col tiles of 256 (N=512)
  const int mt = id >> 1;

  const int rr   = tid >> 3;
  const int xoro = (((tid & 7) ^ (rr & 7)) << 3);

  const unsigned short* pA0; const unsigned short* pA1;
  const unsigned short* pA2; const unsigned short* pA3;
#define MKPA(PS, S) { \
    int m = mt * 256 + (S) * 64 + rr; \
    if (m >= M_TOT) m = M_TOT - 1; \
    PS = hmat + (size_t)m * H_DIM + xoro; }
  MKPA(pA0, 0) MKPA(pA1, 1) MKPA(pA2, 2) MKPA(pA3, 3)
#undef MKPA
  const unsigned short* pB0 = w2t + (size_t)(nt * 256 +   0 + rr) * H_DIM + xoro;
  const unsigned short* pB1 = w2t + (size_t)(nt * 256 +  64 + rr) * H_DIM + xoro;
  const unsigned short* pB2 = w2t + (size_t)(nt * 256 + 128 + rr) * H_DIM + xoro;
  const unsigned short* pB3 = w2t + (size_t)(nt * 256 + 192 + rr) * H_DIM + xoro;

  const int wm = wave >> 2;
  const int wn = wave & 3;
  const int l15 = lane & 15;
  const int slot0 = ((lane >> 4) ^ (lane & 7)) << 4;
  const int aoff  = (wm * 128 + l15) * 128 + slot0;
  const int aoff1 = aoff ^ 64;
  const int boff  = 32768 + (wn * 64 + l15) * 128 + slot0;
  const int boff1 = boff ^ 64;

  f32x4 acc[8][4] = {};

  const int KT = H_DIM / 64;           // 32 K-tiles

#define STAGE_B01(TT) { const size_t ko_ = (size_t)(TT) * 64; \
    unsigned char* d_ = lsm + (((TT) & 1) << 16) + 32768 + tid * 16; \
    async16(pB0 + ko_, d_); async16(pB1 + ko_, d_ + 8192); }
#define STAGE_B23(TT) { const size_t ko_ = (size_t)(TT) * 64; \
    unsigned char* d_ = lsm + (((TT) & 1) << 16) + 32768 + tid * 16; \
    async16(pB2 + ko_, d_ + 16384); async16(pB3 + ko_, d_ + 24576); }
#define STAGE_A02(TT) { const size_t ko_ = (size_t)(TT) * 64; \
    unsigned char* d_ = lsm + (((TT) & 1) << 16) + tid * 16; \
    async16(pA0 + ko_, d_); async16(pA2 + ko_, d_ + 16384); }
#define STAGE_A13(TT) { const size_t ko_ = (size_t)(TT) * 64; \
    unsigned char* d_ = lsm + (((TT) & 1) << 16) + tid * 16; \
    async16(pA1 + ko_, d_ + 8192); async16(pA3 + ko_, d_ + 24576); }

  STAGE_B01(0); STAGE_B23(0); STAGE_A02(0); STAGE_A13(0);
  VM0; SBAR; SCHED0;

  for (int kt = 0; kt < KT; ++kt) {
    const unsigned char* p = lsm + ((kt & 1) << 16);
    const bool last = (kt >= KT - 1);
    bf16x8 a0, a1, a2, a3, a4, a5, a6, a7, b0, b1, b2, b3;

    // q0
    RD_A(0); RD_B(0);
    if (!last) STAGE_B01(kt + 1);
    SBAR; asm volatile("s_waitcnt lgkmcnt(0)" ::: "memory"); SCHED0;
    PRIO1; MFMA16(0, 0); PRIO0;
    SBAR;

    // q1
    RD_B(2);
    if (!last) STAGE_B23(kt + 1);
    SBAR; asm volatile("s_waitcnt lgkmcnt(0)" ::: "memory"); SCHED0;
    PRIO1; MFMA16(0, 2); PRIO0;
    if (last) { VM0; } else { VM4; }
    SBAR;

    // q2
    RD_A(4);
    if (!last) STAGE_A02(kt + 1);
    SBAR; asm volatile("s_waitcnt lgkmcnt(0)" ::: "memory"); SCHED0;
    PRIO1; MFMA16(4, 2); PRIO0;
    SBAR;

    // q3
    RD_B(0);
    if (!last) STAGE_A13(kt + 1);
    SBAR; asm volatile("s_waitcnt lgkmcnt(0)" ::: "memory"); SCHED0;
    PRIO1; MFMA16(4, 0); PRIO0;
    if (last) { VM0; } else { VM2; }
    SBAR;
  }
#undef STAGE_B01
#undef STAGE_B23
#undef STAGE_A02
#undef STAGE_A13

  const int ncol = nt * 256 + wn * 64 + l15;
  const int mrow = mt * 256 + wm * 128 + (lane >> 4) * 4;
#pragma unroll
  for (int u = 0; u < 4; ++u) {
    const int n = ncol + u * 16;
    const float bv = bias2[n];
#pragma unroll
    for (int t = 0; t < 8; ++t) {
#pragma unroll
      for (int r = 0; r < 4; ++r) {
        const int m = mrow + t * 16 + r;
        if (m < M_TOT) {
          const int b = m / L_DIM;
          const int l = m - b * L_DIM;
          out[(size_t)b * SXF + (size_t)l * F_DIM + n] = acc[t][u][r] + bv;
        }
      }
    }
  }
}

// ---------------- conversion / transpose / pad helpers ----------------------
__global__ void cvt_bf16_kernel(const float* __restrict__ in,
                                unsigned short* __restrict__ out, int n4) {
  int idx = blockIdx.x * 256 + threadIdx.x;
  if (idx < n4) {
    float4 v = ((const float4*)in)[idx];
    ushort4 o;
    o.x = f2bf(v.x); o.y = f2bf(v.y); o.z = f2bf(v.z); o.w = f2bf(v.w);
    ((ushort4*)out)[idx] = o;
  }
}

// out[c][r] = bf16(in[r][c]); R, C multiples of 64
__global__ void transpose_cvt_kernel(const float* __restrict__ in,
                                     unsigned short* __restrict__ out, int R, int C) {
  __shared__ unsigned short tile[64][72];
  const int tx = threadIdx.x & 15;
  const int ty = threadIdx.x >> 4;
  const int r0 = blockIdx.x * 64;
  const int c0 = blockIdx.y * 64;
#pragma unroll
  for (int i = 0; i < 4; ++i) {
    const int r = r0 + ty + i * 16;
    float4 v = *(const float4*)(in + (size_t)r * C + c0 + tx * 4);
    tile[ty + i * 16][tx * 4 + 0] = f2bf(v.x);
    tile[ty + i * 16][tx * 4 + 1] = f2bf(v.y);
    tile[ty + i * 16][tx * 4 + 2] = f2bf(v.z);
    tile[ty + i * 16][tx * 4 + 3] = f2bf(v.w);
  }
  __syncthreads();
#pragma unroll
  for (int i = 0; i < 4; ++i) {
    const int c = c0 + ty + i * 16;
    ushort4 o;
    o.x = tile[tx * 4 + 0][ty + i * 16];
    o.y = tile[tx * 4 + 1][ty + i * 16];
    o.z = tile[tx * 4 + 2][ty + i * 16];
    o.w = tile[tx * 4 + 3][ty + i * 16];
    *(ushort4*)(out + (size_t)c * R + r0 + tx * 4) = o;
  }
}

__global__ void zero_pad_kernel(float* __restrict__ out) {
  int idx = blockIdx.x * 256 + threadIdx.x;          // 8 * 15 * 128 float4s
  if (idx < B_DIM * 15 * 128) {
    int b = idx / (15 * 128);
    int rem = idx - b * (15 * 128);
    int l = L_DIM + rem / 128;
    int f4 = rem - (rem / 128) * 128;
    ((float4*)out)[(size_t)b * (SXF / 4) + (size_t)l * 128 + f4] =
        make_float4(0.f, 0.f, 0.f, 0.f);
  }
}

__global__ void fill_sentinel(float* out, int n) {   // distinctive ws-too-small marker
  int idx = blockIdx.x * 256 + threadIdx.x;
  if (idx < n) out[idx] = 12345.0f;
}

extern "C" void kernel_launch(void* const* d_in, const int* in_sizes, int n_in,
                              void* d_out, int out_size, void* d_ws, size_t ws_size,
                              hipStream_t stream) {
  const float* x  = (const float*)d_in[0];
  const float* w1 = (const float*)d_in[1];
  const float* b1 = (const float*)d_in[2];
  const float* w2 = (const float*)d_in[3];
  const float* b2 = (const float*)d_in[4];
  float* out = (float*)d_out;

  const size_t OFF_H   = 0;                               // 32648*2048*2 = 133726208
  const size_t OFF_XB  = 133726208;                       // 16777216*2   = 33554432
  const size_t OFF_W1T = OFF_XB + 33554432;               // 8192*2048*2  = 33554432
  const size_t OFF_W2T = OFF_W1T + 33554432;              // 2048*512*2   = 2097152
  const size_t WS_NEED = OFF_W2T + 2097152;               // ~202.9 MB

  if (ws_size < WS_NEED) {
    fill_sentinel<<<65536, 256, 0, stream>>>(out, out_size);
    return;
  }

  unsigned short* hbuf = (unsigned short*)((char*)d_ws + OFF_H);
  unsigned short* xb   = (unsigned short*)((char*)d_ws + OFF_XB);
  unsigned short* w1t  = (unsigned short*)((char*)d_ws + OFF_W1T);
  unsigned short* w2t  = (unsigned short*)((char*)d_ws + OFF_W2T);

  cvt_bf16_kernel<<<16384, 256, 0, stream>>>(x, xb, 4194304);
  transpose_cvt_kernel<<<dim3(128, 32), 256, 0, stream>>>(w1, w1t, 8192, 2048);
  transpose_cvt_kernel<<<dim3(32, 8), 256, 0, stream>>>(w2, w2t, 2048, 512);
  gemm1_kernel<<<1024, 512, 0, stream>>>(xb, w1t, b1, hbuf);
  gemm2_kernel<<<256, 512, 0, stream>>>(hbuf, w2t, b2, out);
  zero_pad_kernel<<<60, 256, 0, stream>>>(out);
}